// Round 4
// baseline (5865.201 us; speedup 1.0000x reference)
//
#include <hip/hip_runtime.h>
#include <hip/hip_fp16.h>

#define VV 100000
#define BB 2048
#define TT 200
#define GG 192   // 3*C
#define PP 514
#define RPB 8    // batch rows per block (mimn_rnn)

__device__ __forceinline__ float sigmf(float x) { return 1.0f / (1.0f + expf(-x)); }
__device__ __forceinline__ float softplusf(float x) {
    return fmaxf(x, 0.0f) + log1pf(expf(-fabsf(x)));
}
__device__ __forceinline__ float wred64(float x) {
#pragma unroll
    for (int m = 32; m >= 1; m >>= 1) x += __shfl_xor(x, m, 64);
    return x;
}
__device__ __forceinline__ float dot4(float4 w, float4 a) {
    return w.x * a.x + w.y * a.y + w.z * a.z + w.w * a.w;
}
__device__ __forceinline__ float2 h2f2(unsigned int v) {
    __half2 h = *(__half2*)&v;
    return __half22float2(h);
}

// ---------------- K0: per-vocab GI tables (bih folded into GI_item) -------------
__global__ __launch_bounds__(192) void build_tables(
    const float* __restrict__ emb,   // V x 64
    const float* __restrict__ Wih,   // 192 x 256
    const float* __restrict__ bih,   // 192
    float* __restrict__ GIi, float* __restrict__ GIc)  // V x 192 each
{
    __shared__ float sE[64 * 64];
    int tid = threadIdx.x;           // = n
    int v0 = blockIdx.x * 64;
    for (int i = tid; i < 64 * 64; i += 192) {
        int vv = i >> 6, k = i & 63;
        int gv = v0 + vv;
        sE[i] = (gv < VV) ? emb[(size_t)gv * 64 + k] : 0.0f;
    }
    __syncthreads();
    int n = tid;
    float bi = bih[n];
    {
        float4 w[16];
        const float4* wp = (const float4*)(Wih + n * 256);
#pragma unroll
        for (int q = 0; q < 16; ++q) w[q] = wp[q];
        for (int vv = 0; vv < 64; ++vv) {
            int gv = v0 + vv;
            if (gv >= VV) break;
            const float4* e = (const float4*)&sE[vv * 64];
            float acc = bi;
#pragma unroll
            for (int q = 0; q < 16; ++q) acc += dot4(w[q], e[q]);
            GIi[(size_t)gv * GG + n] = acc;
        }
    }
    {
        float4 w[16];
        const float4* wp = (const float4*)(Wih + n * 256 + 64);
#pragma unroll
        for (int q = 0; q < 16; ++q) w[q] = wp[q];
        for (int vv = 0; vv < 64; ++vv) {
            int gv = v0 + vv;
            if (gv >= VV) break;
            const float4* e = (const float4*)&sE[vv * 64];
            float acc = 0.0f;
#pragma unroll
            for (int q = 0; q < 16; ++q) acc += dot4(w[q], e[q]);
            GIc[(size_t)gv * GG + n] = acc;
        }
    }
}

// ---------------- K1: hist_sum + seq_len ----------------------------------------
__global__ __launch_bounds__(128) void hist_stats(
    const int* __restrict__ hist_item, const int* __restrict__ hist_cate,
    const float* __restrict__ mask, const float* __restrict__ emb,
    float* __restrict__ hist_sum, int* __restrict__ seqlen)
{
    int b = blockIdx.x, tid = threadIdx.x;
    const int* hidx = (tid < 64) ? hist_item : hist_cate;   // wave-uniform
    int j = tid & 63;
    float acc = 0.f;
    for (int t = 0; t < TT; ++t) {
        float m = mask[b * TT + t];
        int idx = hidx[b * TT + t];
        acc += m * emb[(size_t)idx * 64 + j];
    }
    hist_sum[(size_t)b * 128 + tid] = acc;
    if (tid < 64) {
        float s = 0.f;
        for (int t = tid; t < TT; t += 64) s += mask[b * TT + t];
        s = wred64(s);
        if (tid == 0) seqlen[b] = (int)(s + 0.5f);
    }
}

// ---------------- K2: recurrence, 512 thr, RPB=8 --------------------------------
// Design law (rounds 0-3): backend allocates 128 VGPR @ 512 thr regardless of
// launch_bounds/waves_per_eu attrs. So structural demand must fit 128:
//   - gate weights (192x192): 72 dw/thread in registers (proven, round 2)
//   - Wp (514x64): fp16 in LDS (65.8 KB), XOR-swizzled rows; NOT streamed from
//     global (round 2: GI gather thrashes L2 -> 6.7 GB latency-bound fetch),
//     NOT in registers (round 0: 8.5 GB scratch spill traffic).
//   - sU partial buffer time-multiplexed (rz -> n -> p) : 32 KB instead of 64.
// Phases/step: ph1a(rz partials) B1 ph2a(reduce->rg,zg) B2 ph1b(n partials +
//   GI commit) B3 ph2b(h update) B4 ph3(p = hn@Wp^T from LDS) B5 ph4(NTM) B6.
// GI gather for t+1 issued at step top, in flight across ph1a/2a/1b.
__global__ __attribute__((amdgpu_flat_work_group_size(512, 512),
                          amdgpu_waves_per_eu(2, 2))) void mimn_rnn(
    const int* __restrict__ hist_item, const int* __restrict__ hist_cate,
    const float* __restrict__ mask,
    const float* __restrict__ Wih,   // 192x256 (cols 128..255 = read part)
    const float* __restrict__ Whh,   // 192x64
    const float* __restrict__ bhh,   // 192
    const float* __restrict__ Wp,    // 514x64
    const float* __restrict__ bp,    // 514
    const float* __restrict__ Wo,    // 64x192
    const float* __restrict__ bo,    // 64
    const float* __restrict__ M0,    // 4x128
    const float* __restrict__ GIi, const float* __restrict__ GIc,
    const int* __restrict__ seqlen,
    float* __restrict__ last_out)    // B x 64
{
    // sU time-multiplexed:
    //   ph1a/2a: rz partials [s*1024 + r*128 + n]   (8192 dw)
    //   ph1b/2b: i_n [s*512 + r*64 + l] (4096) | h_n 4096+[...] (4096)
    //   ph3/4:   p final [r*520 + n] (4160 dw, bias folded)
    __shared__ __align__(16) float sU[8192];
    __shared__ unsigned int sWpU[PP * 32];              // Wp as fp16 pairs, swizzled
    __shared__ __align__(16) float sGI2[2 * RPB * 192]; // double-buffered GIi+GIc
    __shared__ __align__(16) float sAct[RPB * 192];     // [0,128)=read, [128,192)=h
    __shared__ __align__(16) float sHn[RPB * 68];       // unmasked h_new (pad 68)
    __shared__ float sM [RPB * 512];
    __shared__ float sBp[PP];
    __shared__ float sBhh[GG];
    __shared__ float sMask[RPB * TT];
    __shared__ int   sHI[RPB * TT];
    __shared__ int   sHC[RPB * TT];

    const int tid = threadIdx.x;
    const int b0 = blockIdx.x * RPB;
    const int wv = tid >> 6, lane = tid & 63;    // wave id = batch row in ph2/4

    // ---- init staged state ----
    for (int i = tid; i < RPB * 192; i += 512) sAct[i] = 0.f;
    for (int i = tid; i < RPB * 68; i += 512) sHn[i] = 0.f;
    for (int i = tid; i < RPB * 512; i += 512) sM[i] = M0[i & 511];
    for (int i = tid; i < PP; i += 512) sBp[i] = bp[i];
    if (tid < GG) sBhh[tid] = bhh[tid];
    for (int i = tid; i < RPB * TT; i += 512) {
        int r = i / TT, tt = i - r * TT;
        sMask[i] = mask[(size_t)(b0 + r) * TT + tt];
        sHI[i]   = hist_item[(size_t)(b0 + r) * TT + tt];
        sHC[i]   = hist_cate[(size_t)(b0 + r) * TT + tt];
    }
    // Wp -> LDS fp16, swizzled: uint u holds cols (8*c8+2e, +1) of row n at
    // uint-index n*32 + ((c8 ^ ((n>>2)&7))<<2) + e
    for (int i = tid; i < PP * 32; i += 512) {
        int n = i >> 5, u = i & 31;
        int c8 = u >> 2, e = u & 3;
        int c0 = 8 * c8 + 2 * e;
        float f0 = Wp[n * 64 + c0], f1 = Wp[n * 64 + c0 + 1];
        unsigned int lo = (unsigned int)__half_as_ushort(__float2half_rn(f0));
        unsigned int hi = (unsigned int)__half_as_ushort(__float2half_rn(f1));
        sWpU[n * 32 + (((c8 ^ ((n >> 2) & 7))) << 2) + e] = lo | (hi << 16);
    }

    // ---- hoist gate weights: 18 float4 = 72 dwords per thread ----
    const int rowg = tid & 63, sA = tid >> 6;
    const int c0A = 24 * sA;
    const int nA0 = 2 * rowg;           // rows nA0, nA0+1 (0..127): r,z gates
    const int nB  = 128 + rowg;         // row 128..191: n gate
    float4 WA[12];
    float4 WB[6];
#pragma unroll
    for (int jc = 0; jc < 6; ++jc) {
        int c = c0A + 4 * jc;
        if (c < 128) {
#pragma unroll
            for (int ni = 0; ni < 2; ++ni)
                WA[ni * 6 + jc] = *(const float4*)(Wih + (nA0 + ni) * 256 + 128 + c);
            WB[jc] = *(const float4*)(Wih + nB * 256 + 128 + c);
        } else {
#pragma unroll
            for (int ni = 0; ni < 2; ++ni)
                WA[ni * 6 + jc] = *(const float4*)(Whh + (nA0 + ni) * 64 + (c - 128));
            WB[jc] = *(const float4*)(Whh + nB * 64 + (c - 128));
        }
    }
    // act col<128 boundary within this thread's 24-col slice (wave-uniform)
    const int jcut = (sA <= 4) ? 6 : ((sA == 5) ? 2 : 0);

    // phase-3 mapping: 4 Wp rows x 2 batch rows per thread
    const int qrg = tid >> 2;           // row-quad 0..127 (rows 4*qrg..+3)
    const int bp2 = tid & 3;            // batch pair (rows 2*bp2, 2*bp2+1)
    const int wkey = qrg & 7;

    int ts = seqlen[b0 + wv] - 1;
    ts = ts < 0 ? 0 : (ts > TT - 1 ? TT - 1 : ts);
    __syncthreads();

    // ---- initial GI load (t = 0) into buffer 0 (own-wave write, no barrier) ----
    if (lane < 48) {
        int ri = sHI[wv * TT], rc = sHC[wv * TT];
        float4 gi = *(const float4*)(GIi + (size_t)ri * GG + lane * 4);
        float4 gc = *(const float4*)(GIc + (size_t)rc * GG + lane * 4);
        *(float4*)&sGI2[wv * 192 + lane * 4] =
            make_float4(gi.x + gc.x, gi.y + gc.y, gi.z + gc.z, gi.w + gc.w);
    }

    for (int t = 0; t < TT; ++t) {
        // ---- GI prefetch issue for t+1 (in flight across ph1a/2a/1b) ----
        float4 gi4 = make_float4(0.f, 0.f, 0.f, 0.f);
        float4 gc4 = make_float4(0.f, 0.f, 0.f, 0.f);
        if (lane < 48) {
            int tn = (t + 1 < TT) ? t + 1 : TT - 1;
            int ri = sHI[wv * TT + tn], rc = sHC[wv * TT + tn];
            gi4 = *(const float4*)(GIi + (size_t)ri * GG + lane * 4);
            gc4 = *(const float4*)(GIc + (size_t)rc * GG + lane * 4);
        }
        // ---- phase 1a: r,z partials (2 rows x 24 cols) ----
        {
            float acc0[8], acc1[8];
#pragma unroll
            for (int r = 0; r < 8; ++r) { acc0[r] = 0.f; acc1[r] = 0.f; }
#pragma unroll
            for (int jc = 0; jc < 6; ++jc) {
#pragma unroll
                for (int r = 0; r < 8; ++r) {
                    float4 a = *(const float4*)&sAct[r * 192 + c0A + 4 * jc];
                    acc0[r] += dot4(WA[jc], a);
                    acc1[r] += dot4(WA[6 + jc], a);
                }
            }
#pragma unroll
            for (int r = 0; r < 8; ++r)
                *(float2*)&sU[sA * 1024 + r * 128 + nA0] = make_float2(acc0[r], acc1[r]);
        }
        __syncthreads();                                   // B1
        // ---- phase 2a: reduce r,z -> rg,zg (kept in regs to ph2b) ----
        float rg, zg;
        {
            const float* gbuf = &sGI2[(t & 1) * 1536 + wv * 192];
            float g_r = sBhh[lane] + gbuf[lane];
            float g_z = sBhh[64 + lane] + gbuf[64 + lane];
#pragma unroll
            for (int s = 0; s < 8; ++s) {
                g_r += sU[s * 1024 + wv * 128 + lane];
                g_z += sU[s * 1024 + wv * 128 + 64 + lane];
            }
            rg = sigmf(g_r);
            zg = sigmf(g_z);
        }
        __syncthreads();                                   // B2
        // ---- phase 1b: n partials (read/h split) into reused sU + GI commit ----
        {
            float accR[8], accH[8];
#pragma unroll
            for (int r = 0; r < 8; ++r) { accR[r] = 0.f; accH[r] = 0.f; }
#pragma unroll
            for (int jc = 0; jc < 6; ++jc) {
                if (jc < jcut) {          // wave-uniform branch, static acc index
#pragma unroll
                    for (int r = 0; r < 8; ++r)
                        accR[r] += dot4(WB[jc], *(const float4*)&sAct[r * 192 + c0A + 4 * jc]);
                } else {
#pragma unroll
                    for (int r = 0; r < 8; ++r)
                        accH[r] += dot4(WB[jc], *(const float4*)&sAct[r * 192 + c0A + 4 * jc]);
                }
            }
#pragma unroll
            for (int r = 0; r < 8; ++r) {
                sU[sA * 512 + r * 64 + rowg]        = accR[r];
                sU[4096 + sA * 512 + r * 64 + rowg] = accH[r];
            }
            if (lane < 48)
                *(float4*)&sGI2[((t + 1) & 1) * 1536 + wv * 192 + lane * 4] =
                    make_float4(gi4.x + gc4.x, gi4.y + gc4.y, gi4.z + gc4.z, gi4.w + gc4.w);
        }
        __syncthreads();                                   // B3
        // ---- phase 2b: finish GRU, commit h ----
        {
            const float* gbuf = &sGI2[(t & 1) * 1536 + wv * 192];
            float i_n = gbuf[128 + lane];
            float h_n = sBhh[128 + lane];
#pragma unroll
            for (int s = 0; s < 8; ++s) {
                i_n += sU[s * 512 + wv * 64 + lane];
                h_n += sU[4096 + s * 512 + wv * 64 + lane];
            }
            float ng = tanhf(i_n + rg * h_n);
            float h_old = sAct[wv * 192 + 128 + lane];
            float hn = (1.f - zg) * ng + zg * h_old;
            float mt = sMask[wv * TT + t];
            sHn[wv * 68 + lane] = hn;
            sAct[wv * 192 + 128 + lane] = (mt > 0.f) ? hn : h_old;
        }
        __syncthreads();                                   // B4
        // ---- phase 3: p = h_new @ Wp^T from LDS-fp16 Wp (bias folded) ----
        {
            const int rb0 = 2 * bp2;
            float acc[4][2];
#pragma unroll
            for (int j = 0; j < 4; ++j) { acc[j][0] = 0.f; acc[j][1] = 0.f; }
#pragma unroll
            for (int c8 = 0; c8 < 8; ++c8) {
                const int slot = ((c8 ^ wkey) << 2);
                float4 ha0 = *(const float4*)&sHn[rb0 * 68 + 8 * c8];
                float4 hb0 = *(const float4*)&sHn[rb0 * 68 + 8 * c8 + 4];
                float4 ha1 = *(const float4*)&sHn[(rb0 + 1) * 68 + 8 * c8];
                float4 hb1 = *(const float4*)&sHn[(rb0 + 1) * 68 + 8 * c8 + 4];
#pragma unroll
                for (int j = 0; j < 4; ++j) {
                    uint4 wq = *(const uint4*)&sWpU[(4 * qrg + j) * 32 + slot];
                    float2 f0 = h2f2(wq.x), f1 = h2f2(wq.y);
                    float2 f2v = h2f2(wq.z), f3 = h2f2(wq.w);
                    acc[j][0] += f0.x * ha0.x + f0.y * ha0.y + f1.x * ha0.z + f1.y * ha0.w
                               + f2v.x * hb0.x + f2v.y * hb0.y + f3.x * hb0.z + f3.y * hb0.w;
                    acc[j][1] += f0.x * ha1.x + f0.y * ha1.y + f1.x * ha1.z + f1.y * ha1.w
                               + f2v.x * hb1.x + f2v.y * hb1.y + f3.x * hb1.z + f3.y * hb1.w;
                }
            }
#pragma unroll
            for (int j = 0; j < 4; ++j) {
                float bpj = sBp[4 * qrg + j];
                sU[rb0 * 520 + 4 * qrg + j]       = acc[j][0] + bpj;
                sU[(rb0 + 1) * 520 + 4 * qrg + j] = acc[j][1] + bpj;
            }
        }
        if (tid < 4) {   // rows 512,513 (quad key 0), batch pair = tid
            const int rb0 = 2 * tid;
            float a512[2], a513[2];
            a512[0] = a512[1] = a513[0] = a513[1] = 0.f;
#pragma unroll
            for (int c8 = 0; c8 < 8; ++c8) {
                const int slot = c8 << 2;
                uint4 wa = *(const uint4*)&sWpU[512 * 32 + slot];
                uint4 wb = *(const uint4*)&sWpU[513 * 32 + slot];
                float4 ha0 = *(const float4*)&sHn[rb0 * 68 + 8 * c8];
                float4 hb0 = *(const float4*)&sHn[rb0 * 68 + 8 * c8 + 4];
                float4 ha1 = *(const float4*)&sHn[(rb0 + 1) * 68 + 8 * c8];
                float4 hb1 = *(const float4*)&sHn[(rb0 + 1) * 68 + 8 * c8 + 4];
                float2 f0 = h2f2(wa.x), f1 = h2f2(wa.y), f2v = h2f2(wa.z), f3 = h2f2(wa.w);
                a512[0] += f0.x * ha0.x + f0.y * ha0.y + f1.x * ha0.z + f1.y * ha0.w
                         + f2v.x * hb0.x + f2v.y * hb0.y + f3.x * hb0.z + f3.y * hb0.w;
                a512[1] += f0.x * ha1.x + f0.y * ha1.y + f1.x * ha1.z + f1.y * ha1.w
                         + f2v.x * hb1.x + f2v.y * hb1.y + f3.x * hb1.z + f3.y * hb1.w;
                f0 = h2f2(wb.x); f1 = h2f2(wb.y); f2v = h2f2(wb.z); f3 = h2f2(wb.w);
                a513[0] += f0.x * ha0.x + f0.y * ha0.y + f1.x * ha0.z + f1.y * ha0.w
                         + f2v.x * hb0.x + f2v.y * hb0.y + f3.x * hb0.z + f3.y * hb0.w;
                a513[1] += f0.x * ha1.x + f0.y * ha1.y + f1.x * ha1.z + f1.y * ha1.w
                         + f2v.x * hb1.x + f2v.y * hb1.y + f3.x * hb1.z + f3.y * hb1.w;
            }
            float b512 = sBp[512], b513 = sBp[513];
            sU[rb0 * 520 + 512] = a512[0] + b512;
            sU[(rb0 + 1) * 520 + 512] = a512[1] + b512;
            sU[rb0 * 520 + 513] = a513[0] + b513;
            sU[(rb0 + 1) * 520 + 513] = a513[1] + b513;
        }
        __syncthreads();                                   // B5
        // ---- phase 4: NTM addressing, one wave per row ----
        {
            const int row = wv;
            const int pb = row * 520;
#define PV(n) (sU[pb + (n)])
            float kr1 = tanhf(PV(lane)),       kr2 = tanhf(PV(64 + lane));
            float beta_r = softplusf(PV(128));
            float kw1 = tanhf(PV(129 + lane)), kw2 = tanhf(PV(193 + lane));
            float beta_w = softplusf(PV(257));
            float er1 = sigmf(PV(258 + lane)), er2 = sigmf(PV(322 + lane));
            float ad1 = tanhf(PV(386 + lane)), ad2 = tanhf(PV(450 + lane));
#undef PV
            float M1[4], M2[4];
#pragma unroll
            for (int s = 0; s < 4; ++s) {
                M1[s] = sM[row * 512 + s * 128 + lane];
                M2[s] = sM[row * 512 + s * 128 + 64 + lane];
            }
            float nkr = sqrtf(wred64(kr1 * kr1 + kr2 * kr2)) + 1e-8f;
            float nkw = sqrtf(wred64(kw1 * kw1 + kw2 * kw2)) + 1e-8f;
            float Kr[4], Kw[4];
#pragma unroll
            for (int s = 0; s < 4; ++s) {
                float nM = sqrtf(wred64(M1[s] * M1[s] + M2[s] * M2[s])) + 1e-8f;
                float dr = wred64(kr1 * M1[s] + kr2 * M2[s]);
                float dw = wred64(kw1 * M1[s] + kw2 * M2[s]);
                Kr[s] = dr / (nkr * nM);
                Kw[s] = dw / (nkw * nM);
            }
            float wr_[4], ww_[4];
            {
                float mx = fmaxf(fmaxf(beta_r * Kr[0], beta_r * Kr[1]),
                                 fmaxf(beta_r * Kr[2], beta_r * Kr[3]));
                float sum = 0.f;
#pragma unroll
                for (int s = 0; s < 4; ++s) { wr_[s] = expf(beta_r * Kr[s] - mx); sum += wr_[s]; }
                float inv = 1.f / sum;
#pragma unroll
                for (int s = 0; s < 4; ++s) wr_[s] *= inv;
            }
            {
                float mx = fmaxf(fmaxf(beta_w * Kw[0], beta_w * Kw[1]),
                                 fmaxf(beta_w * Kw[2], beta_w * Kw[3]));
                float sum = 0.f;
#pragma unroll
                for (int s = 0; s < 4; ++s) { ww_[s] = expf(beta_w * Kw[s] - mx); sum += ww_[s]; }
                float inv = 1.f / sum;
#pragma unroll
                for (int s = 0; s < 4; ++s) ww_[s] *= inv;
            }
            float rn1 = 0.f, rn2 = 0.f;
#pragma unroll
            for (int s = 0; s < 4; ++s) { rn1 += wr_[s] * M1[s]; rn2 += wr_[s] * M2[s]; }
            float mt = sMask[row * TT + t];
            bool vld = mt > 0.f;
            if (vld) {
#pragma unroll
                for (int s = 0; s < 4; ++s) {
                    sM[row * 512 + s * 128 + lane]      = M1[s] * (1.f - ww_[s] * er1) + ww_[s] * ad1;
                    sM[row * 512 + s * 128 + 64 + lane] = M2[s] * (1.f - ww_[s] * er2) + ww_[s] * ad2;
                }
                sAct[row * 192 + lane]      = rn1;   // committed read
                sAct[row * 192 + 64 + lane] = rn2;
            }
            if (t == ts) {
                // out = [h_new, read_new] @ Wo^T + bo  (unmasked values)
                // stash rn1/rn2 in the *current* GI buffer (dead after ph2b)
                float* stash = &sGI2[(t & 1) * 1536 + row * 192];
                stash[lane] = rn1; stash[64 + lane] = rn2;
                __asm__ volatile("s_waitcnt lgkmcnt(0)" ::: "memory");
                float acc = bo[lane];
                const float* wo = Wo + lane * GG;
                for (int k = 0; k < 64; ++k)  acc += sHn[row * 68 + k] * wo[k];
                for (int k = 0; k < 128; ++k) acc += stash[k] * wo[64 + k];
                if (!vld) acc = 0.f;
                last_out[(size_t)(b0 + row) * 64 + lane] = acc;
            }
        }
        __syncthreads();                                   // B6
    }
}

// ---------------- K3: final MLP head --------------------------------------------
__global__ __launch_bounds__(128) void final_mlp(
    const int* __restrict__ item, const int* __restrict__ cate,
    const float* __restrict__ emb,
    const float* __restrict__ hist_sum, const float* __restrict__ last_out,
    const float* __restrict__ fc1w, const float* __restrict__ fc1b,
    const float* __restrict__ pa1,
    const float* __restrict__ fc2w, const float* __restrict__ fc2b,
    const float* __restrict__ pa2,
    const float* __restrict__ fc3w, const float* __restrict__ fc3b,
    float* __restrict__ out)
{
    __shared__ float sX[320], sH1[200], sH2[80];
    int b = blockIdx.x, tid = threadIdx.x;
    int it = item[b], ct = cate[b];
    for (int i = tid; i < 320; i += 128) {
        float val;
        if (i < 64)       val = emb[(size_t)it * 64 + i];
        else if (i < 128) val = emb[(size_t)ct * 64 + (i - 64)];
        else if (i < 256) val = hist_sum[(size_t)b * 128 + (i - 128)];
        else              val = last_out[(size_t)b * 64 + (i - 256)];
        sX[i] = val;
    }
    __syncthreads();
    float a1 = pa1[0];
    for (int o = tid; o < 200; o += 128) {
        const float4* w = (const float4*)(fc1w + o * 320);
        float acc = fc1b[o];
#pragma unroll
        for (int q = 0; q < 80; ++q) acc += dot4(w[q], *(const float4*)&sX[q * 4]);
        sH1[o] = acc > 0.f ? acc : a1 * acc;
    }
    __syncthreads();
    float a2 = pa2[0];
    for (int o = tid; o < 80; o += 128) {
        const float4* w = (const float4*)(fc2w + o * 200);
        float acc = fc2b[o];
#pragma unroll
        for (int q = 0; q < 50; ++q) acc += dot4(w[q], *(const float4*)&sH1[q * 4]);
        sH2[o] = acc > 0.f ? acc : a2 * acc;
    }
    __syncthreads();
    if (tid < 2) {
        const float4* w = (const float4*)(fc3w + tid * 80);
        float acc = fc3b[tid];
#pragma unroll
        for (int q = 0; q < 20; ++q) acc += dot4(w[q], *(const float4*)&sH2[q * 4]);
        out[b * 2 + tid] = acc;
    }
}

extern "C" void kernel_launch(void* const* d_in, const int* in_sizes, int n_in,
                              void* d_out, int out_size, void* d_ws, size_t ws_size,
                              hipStream_t stream) {
    (void)in_sizes; (void)n_in; (void)out_size; (void)ws_size;
    const int*   item      = (const int*)d_in[0];
    const int*   cate      = (const int*)d_in[1];
    const int*   hist_item = (const int*)d_in[2];
    const int*   hist_cate = (const int*)d_in[3];
    const float* mask = (const float*)d_in[4];
    const float* emb  = (const float*)d_in[5];
    const float* Wih  = (const float*)d_in[6];
    const float* Whh  = (const float*)d_in[7];
    const float* bih  = (const float*)d_in[8];
    const float* bhh  = (const float*)d_in[9];
    const float* Wp   = (const float*)d_in[10];
    const float* bp   = (const float*)d_in[11];
    const float* Wo   = (const float*)d_in[12];
    const float* bo   = (const float*)d_in[13];
    const float* M0   = (const float*)d_in[14];
    const float* fc1w = (const float*)d_in[15];
    const float* fc1b = (const float*)d_in[16];
    const float* pa1  = (const float*)d_in[17];
    const float* fc2w = (const float*)d_in[18];
    const float* fc2b = (const float*)d_in[19];
    const float* pa2  = (const float*)d_in[20];
    const float* fc3w = (const float*)d_in[21];
    const float* fc3b = (const float*)d_in[22];

    float* GIi = (float*)d_ws;                                   // V*192 f32
    float* GIc = GIi + (size_t)VV * GG;                          // V*192 f32
    float* hist_sum = GIc + (size_t)VV * GG;                     // B*128 f32
    float* last_out = hist_sum + (size_t)BB * 128;               // B*64 f32
    int* seqlen = (int*)(last_out + (size_t)BB * 64);            // B int

    build_tables<<<(VV + 63) / 64, 192, 0, stream>>>(emb, Wih, bih, GIi, GIc);
    hist_stats<<<BB, 128, 0, stream>>>(hist_item, hist_cate, mask, emb, hist_sum, seqlen);
    mimn_rnn<<<BB / RPB, 512, 0, stream>>>(hist_item, hist_cate, mask, Wih, Whh, bhh,
                                           Wp, bp, Wo, bo, M0, GIi, GIc, seqlen, last_out);
    final_mlp<<<BB, 128, 0, stream>>>(item, cate, emb, hist_sum, last_out,
                                      fc1w, fc1b, pa1, fc2w, fc2b, pa2, fc3w, fc3b,
                                      (float*)d_out);
}

// Round 5
// 1593.780 us; speedup vs baseline: 3.6801x; 3.6801x over previous
//
#include <hip/hip_runtime.h>

#define VV 100000
#define BB 2048
#define TT 200
#define GG 192   // 3*C
#define PP 514
#define RPB 8    // batch rows per block (mimn_rnn)

typedef _Float16 half8 __attribute__((ext_vector_type(8)));
typedef float floatx4 __attribute__((ext_vector_type(4)));
#define MFMA16(a, b, c) __builtin_amdgcn_mfma_f32_16x16x32_f16((a), (b), (c), 0, 0, 0)

__device__ __forceinline__ float sigmf(float x) { return 1.0f / (1.0f + expf(-x)); }
__device__ __forceinline__ float softplusf(float x) {
    return fmaxf(x, 0.0f) + log1pf(expf(-fabsf(x)));
}
__device__ __forceinline__ float wred64(float x) {
#pragma unroll
    for (int m = 32; m >= 1; m >>= 1) x += __shfl_xor(x, m, 64);
    return x;
}
__device__ __forceinline__ float dot4(float4 w, float4 a) {
    return w.x * a.x + w.y * a.y + w.z * a.z + w.w * a.w;
}

// ---------------- K0: per-vocab GI tables (bih folded into GI_item) -------------
__global__ __launch_bounds__(192) void build_tables(
    const float* __restrict__ emb,   // V x 64
    const float* __restrict__ Wih,   // 192 x 256
    const float* __restrict__ bih,   // 192
    float* __restrict__ GIi, float* __restrict__ GIc)  // V x 192 each
{
    __shared__ float sE[64 * 64];
    int tid = threadIdx.x;           // = n
    int v0 = blockIdx.x * 64;
    for (int i = tid; i < 64 * 64; i += 192) {
        int vv = i >> 6, k = i & 63;
        int gv = v0 + vv;
        sE[i] = (gv < VV) ? emb[(size_t)gv * 64 + k] : 0.0f;
    }
    __syncthreads();
    int n = tid;
    float bi = bih[n];
    {
        float4 w[16];
        const float4* wp = (const float4*)(Wih + n * 256);
#pragma unroll
        for (int q = 0; q < 16; ++q) w[q] = wp[q];
        for (int vv = 0; vv < 64; ++vv) {
            int gv = v0 + vv;
            if (gv >= VV) break;
            const float4* e = (const float4*)&sE[vv * 64];
            float acc = bi;
#pragma unroll
            for (int q = 0; q < 16; ++q) acc += dot4(w[q], e[q]);
            GIi[(size_t)gv * GG + n] = acc;
        }
    }
    {
        float4 w[16];
        const float4* wp = (const float4*)(Wih + n * 256 + 64);
#pragma unroll
        for (int q = 0; q < 16; ++q) w[q] = wp[q];
        for (int vv = 0; vv < 64; ++vv) {
            int gv = v0 + vv;
            if (gv >= VV) break;
            const float4* e = (const float4*)&sE[vv * 64];
            float acc = 0.0f;
#pragma unroll
            for (int q = 0; q < 16; ++q) acc += dot4(w[q], e[q]);
            GIc[(size_t)gv * GG + n] = acc;
        }
    }
}

// ---------------- K1: hist_sum + seq_len ----------------------------------------
__global__ __launch_bounds__(128) void hist_stats(
    const int* __restrict__ hist_item, const int* __restrict__ hist_cate,
    const float* __restrict__ mask, const float* __restrict__ emb,
    float* __restrict__ hist_sum, int* __restrict__ seqlen)
{
    int b = blockIdx.x, tid = threadIdx.x;
    const int* hidx = (tid < 64) ? hist_item : hist_cate;   // wave-uniform
    int j = tid & 63;
    float acc = 0.f;
    for (int t = 0; t < TT; ++t) {
        float m = mask[b * TT + t];
        int idx = hidx[b * TT + t];
        acc += m * emb[(size_t)idx * 64 + j];
    }
    hist_sum[(size_t)b * 128 + tid] = acc;
    if (tid < 64) {
        float s = 0.f;
        for (int t = tid; t < TT; t += 64) s += mask[b * TT + t];
        s = wred64(s);
        if (tid == 0) seqlen[b] = (int)(s + 0.5f);
    }
}

// ---------------- K2: recurrence, 768 thr (12 waves), RPB=8, MFMA ---------------
// Rounds 0-4 law: the backend will not keep >~50 dw of per-thread weights
// resident in a VALU-GEMM structure (spill/remat/stream all cost GBs of HBM
// traffic). MFMA fragments break the bind: per-wave weight residency is
// 48 VGPR/thread total and the matrix pipe does the MACs.
//   gates: C[16x192] = act16[16x192(f16)] @ W'^T, W'=[Wih_read|Whh] per N-tile.
//     waves 0-7: r,z tiles (N-tile=wv, K=192, 6 frag = 24 VGPR)
//     waves 8-11: n-gate tile (wv-8), i_n (K=0..127) / h_n (K=128..191) kept in
//     SEPARATE accumulators (rg multiplies h_n only).
//   p: C[16x528] = hn16[16x64(f16)] @ Wp^T; 33 N-tiles strided over 12 waves
//     (rows 514-527 zero-padded in fragments). 24 VGPR.
// Recurrent h carried in f32 (sHf); f16 only on GEMM inputs (non-compounding).
// M rows 8-15 of the 16-row tile are zero padding (RPB=8).
// Barriers: 4/step. LDS ~97.5 KB -> 1 block/CU, 12 waves = 3/SIMD.
__global__ __attribute__((amdgpu_flat_work_group_size(768, 768))) void mimn_rnn(
    const int* __restrict__ hist_item, const int* __restrict__ hist_cate,
    const float* __restrict__ mask,
    const float* __restrict__ Wih,   // 192x256 (cols 128..255 = read part)
    const float* __restrict__ Whh,   // 192x64
    const float* __restrict__ bhh,   // 192
    const float* __restrict__ Wp,    // 514x64
    const float* __restrict__ bp,    // 514
    const float* __restrict__ Wo,    // 64x192
    const float* __restrict__ bo,    // 64
    const float* __restrict__ M0,    // 4x128
    const float* __restrict__ GIi, const float* __restrict__ GIc,
    const int* __restrict__ seqlen,
    float* __restrict__ last_out)    // B x 64
{
    // sU time-multiplexed (f32):
    //  ph1/2: rzU [m][n<128] stride 132 @0 (2112) | inU [m][n64] stride 68 @2112
    //         (1088) | hnU stride 68 @3200 (1088)
    //  ph3/4: pU [m][n<528] stride 532 @0 (8512)
    __shared__ __align__(16) float sU[8512];
    __shared__ __align__(16) _Float16 act16[16 * 200]; // [0,128)=read,[128,192)=h
    __shared__ __align__(16) _Float16 hn16[16 * 72];   // unmasked h_new (f16)
    __shared__ __align__(16) float sGI2[2 * RPB * 192];
    __shared__ float sHf[RPB * 64];                    // committed h (f32 carrier)
    __shared__ float sHnF[RPB * 64];                   // unmasked h_new (f32)
    __shared__ float sM [RPB * 512];
    __shared__ float sBp[PP];
    __shared__ float sBhh[GG];
    __shared__ float sMask[RPB * TT];
    __shared__ int   sHI[RPB * TT];
    __shared__ int   sHC[RPB * TT];

    const int tid = threadIdx.x;
    const int b0 = blockIdx.x * RPB;
    const int wv = tid >> 6, lane = tid & 63;
    const int nlo = lane & 15, kg = lane >> 4;   // MFMA: n/m-low, k-group

    // ---- init staged state ----
    for (int i = tid; i < 16 * 200; i += 768) act16[i] = (_Float16)0.f;
    for (int i = tid; i < 16 * 72; i += 768) hn16[i] = (_Float16)0.f;
    for (int i = tid; i < RPB * 64; i += 768) { sHf[i] = 0.f; sHnF[i] = 0.f; }
    for (int i = tid; i < RPB * 512; i += 768) sM[i] = M0[i & 511];
    for (int i = tid; i < PP; i += 768) sBp[i] = bp[i];
    if (tid < GG) sBhh[tid] = bhh[tid];
    for (int i = tid; i < RPB * TT; i += 768) {
        int r = i / TT, tt = i - r * TT;
        sMask[i] = mask[(size_t)(b0 + r) * TT + tt];
        sHI[i]   = hist_item[(size_t)(b0 + r) * TT + tt];
        sHC[i]   = hist_cate[(size_t)(b0 + r) * TT + tt];
    }

    // ---- weight fragments (one-time global loads) ----
    // B-frag layout for 16x16x32_f16: lane holds W[n=16*tile+nlo][k=32*kb+8*kg+j]
    half8 WG[6];
    if (wv < 8) {               // r,z rows: n in [0,128), K=192 combined
        int n = 16 * wv + nlo;
#pragma unroll
        for (int kb = 0; kb < 6; ++kb) {
            half8 f;
#pragma unroll
            for (int j = 0; j < 8; ++j) {
                int k = 32 * kb + 8 * kg + j;
                float w = (k < 128) ? Wih[n * 256 + 128 + k] : Whh[n * 64 + (k - 128)];
                f[j] = (_Float16)w;
            }
            WG[kb] = f;
        }
    } else {                    // n-gate rows: n in [128,192)
        int n = 128 + 16 * (wv - 8) + nlo;
#pragma unroll
        for (int kb = 0; kb < 4; ++kb) {   // i_n part: k = act cols 0..127 (read)
            half8 f;
#pragma unroll
            for (int j = 0; j < 8; ++j) f[j] = (_Float16)Wih[n * 256 + 128 + 32 * kb + 8 * kg + j];
            WG[kb] = f;
        }
#pragma unroll
        for (int kb = 0; kb < 2; ++kb) {   // h_n part: k2 = 0..63 (h)
            half8 f;
#pragma unroll
            for (int j = 0; j < 8; ++j) f[j] = (_Float16)Whh[n * 64 + 32 * kb + 8 * kg + j];
            WG[4 + kb] = f;
        }
    }
    // Wp fragments: N-tiles wv, wv+12, wv+24 (<33); rows >=514 zero-padded.
    const int np0 = wv, np1 = wv + 12, np2 = wv + 24;
    const bool v2 = (np2 < 33);
    half8 WP0[2], WP1[2], WP2[2];
#pragma unroll
    for (int kb = 0; kb < 2; ++kb) {
        half8 f0, f1, f2;
        int n0 = 16 * np0 + nlo, n1 = 16 * np1 + nlo, n2 = 16 * np2 + nlo;
#pragma unroll
        for (int j = 0; j < 8; ++j) {
            int k = 32 * kb + 8 * kg + j;
            f0[j] = (_Float16)((n0 < PP) ? Wp[n0 * 64 + k] : 0.f);
            f1[j] = (_Float16)((n1 < PP) ? Wp[n1 * 64 + k] : 0.f);
            f2[j] = (_Float16)((v2 && n2 < PP) ? Wp[n2 * 64 + k] : 0.f);
        }
        WP0[kb] = f0; WP1[kb] = f1; WP2[kb] = f2;
    }

    int ts = seqlen[b0 + ((wv < 8) ? wv : 0)] - 1;
    ts = ts < 0 ? 0 : (ts > TT - 1 ? TT - 1 : ts);
    __syncthreads();

    // ---- initial GI load (t = 0) into buffer 0 ----
    if (wv < 8 && lane < 48) {
        int ri = sHI[wv * TT], rc = sHC[wv * TT];
        float4 gi = *(const float4*)(GIi + (size_t)ri * GG + lane * 4);
        float4 gc = *(const float4*)(GIc + (size_t)rc * GG + lane * 4);
        *(float4*)&sGI2[wv * 192 + lane * 4] =
            make_float4(gi.x + gc.x, gi.y + gc.y, gi.z + gc.z, gi.w + gc.w);
    }

    for (int t = 0; t < TT; ++t) {
        // ---- GI prefetch issue for t+1 (in flight across ph1/ph2) ----
        float4 gi4 = make_float4(0.f, 0.f, 0.f, 0.f);
        float4 gc4 = make_float4(0.f, 0.f, 0.f, 0.f);
        if (wv < 8 && lane < 48) {
            int tn = (t + 1 < TT) ? t + 1 : TT - 1;
            int ri = sHI[wv * TT + tn], rc = sHC[wv * TT + tn];
            gi4 = *(const float4*)(GIi + (size_t)ri * GG + lane * 4);
            gc4 = *(const float4*)(GIc + (size_t)rc * GG + lane * 4);
        }
        // ---- phase 1: gate GEMMs (A rows = batch, from act16 f16) ----
        {
            const int abase = nlo * 200 + 8 * kg;
            half8 a0 = *(const half8*)&act16[abase];
            half8 a1 = *(const half8*)&act16[abase + 32];
            half8 a2 = *(const half8*)&act16[abase + 64];
            if (wv < 8) {
                floatx4 acc = {0.f, 0.f, 0.f, 0.f};
                acc = MFMA16(a0, WG[0], acc);
                acc = MFMA16(a1, WG[1], acc);
                acc = MFMA16(a2, WG[2], acc);
                a0 = *(const half8*)&act16[abase + 96];
                a1 = *(const half8*)&act16[abase + 128];
                a2 = *(const half8*)&act16[abase + 160];
                acc = MFMA16(a0, WG[3], acc);
                acc = MFMA16(a1, WG[4], acc);
                acc = MFMA16(a2, WG[5], acc);
                int n = 16 * wv + nlo, mb = 4 * kg;
#pragma unroll
                for (int q = 0; q < 4; ++q) sU[(mb + q) * 132 + n] = acc[q];
            } else {
                floatx4 accI = {0.f, 0.f, 0.f, 0.f};
                floatx4 accH = {0.f, 0.f, 0.f, 0.f};
                accI = MFMA16(a0, WG[0], accI);
                accI = MFMA16(a1, WG[1], accI);
                accI = MFMA16(a2, WG[2], accI);
                a0 = *(const half8*)&act16[abase + 96];
                accI = MFMA16(a0, WG[3], accI);
                a1 = *(const half8*)&act16[abase + 128];
                a2 = *(const half8*)&act16[abase + 160];
                accH = MFMA16(a1, WG[4], accH);
                accH = MFMA16(a2, WG[5], accH);
                int n64 = 16 * (wv - 8) + nlo, mb = 4 * kg;
#pragma unroll
                for (int q = 0; q < 4; ++q) {
                    sU[2112 + (mb + q) * 68 + n64] = accI[q];
                    sU[3200 + (mb + q) * 68 + n64] = accH[q];
                }
            }
        }
        __syncthreads();                                   // B1
        // ---- phase 2: GRU gates; commit h (waves 0-7, row = wave) ----
        if (wv < 8) {
            const int r = wv;
            const float* gbuf = &sGI2[(t & 1) * 1536 + r * 192];
            float g_r = sU[r * 132 + lane] + gbuf[lane] + sBhh[lane];
            float g_z = sU[r * 132 + 64 + lane] + gbuf[64 + lane] + sBhh[64 + lane];
            float i_n = sU[2112 + r * 68 + lane] + gbuf[128 + lane];
            float h_n = sU[3200 + r * 68 + lane] + sBhh[128 + lane];
            float rg = sigmf(g_r);
            float zg = sigmf(g_z);
            float ng = tanhf(i_n + rg * h_n);
            float h_old = sHf[r * 64 + lane];
            float hn = (1.f - zg) * ng + zg * h_old;
            float mt = sMask[r * TT + t];
            float hc = (mt > 0.f) ? hn : h_old;
            sHf[r * 64 + lane] = hc;
            act16[r * 200 + 128 + lane] = (_Float16)hc;
            hn16[r * 72 + lane] = (_Float16)hn;
            sHnF[r * 64 + lane] = hn;
        }
        __syncthreads();                                   // B2
        // ---- phase 3: p = hn @ Wp^T (all 12 waves, MFMA) + GI commit ----
        {
            const int bbase = nlo * 72 + 8 * kg;
            half8 b0f = *(const half8*)&hn16[bbase];
            half8 b1f = *(const half8*)&hn16[bbase + 32];
            const int mb = 4 * kg;
            {
                floatx4 acc = {0.f, 0.f, 0.f, 0.f};
                acc = MFMA16(b0f, WP0[0], acc);
                acc = MFMA16(b1f, WP0[1], acc);
                int n = 16 * np0 + nlo;
#pragma unroll
                for (int q = 0; q < 4; ++q) sU[(mb + q) * 532 + n] = acc[q];
            }
            {
                floatx4 acc = {0.f, 0.f, 0.f, 0.f};
                acc = MFMA16(b0f, WP1[0], acc);
                acc = MFMA16(b1f, WP1[1], acc);
                int n = 16 * np1 + nlo;
#pragma unroll
                for (int q = 0; q < 4; ++q) sU[(mb + q) * 532 + n] = acc[q];
            }
            if (v2) {
                floatx4 acc = {0.f, 0.f, 0.f, 0.f};
                acc = MFMA16(b0f, WP2[0], acc);
                acc = MFMA16(b1f, WP2[1], acc);
                int n = 16 * np2 + nlo;
#pragma unroll
                for (int q = 0; q < 4; ++q) sU[(mb + q) * 532 + n] = acc[q];
            }
        }
        if (wv < 8 && lane < 48)
            *(float4*)&sGI2[((t + 1) & 1) * 1536 + wv * 192 + lane * 4] =
                make_float4(gi4.x + gc4.x, gi4.y + gc4.y, gi4.z + gc4.z, gi4.w + gc4.w);
        __syncthreads();                                   // B3
        // ---- phase 4: NTM addressing, one wave per row (waves 0-7) ----
        if (wv < 8) {
            const int row = wv;
            const int pb = row * 532;
#define PV(n) (sU[pb + (n)] + sBp[(n)])
            float kr1 = tanhf(PV(lane)),       kr2 = tanhf(PV(64 + lane));
            float beta_r = softplusf(PV(128));
            float kw1 = tanhf(PV(129 + lane)), kw2 = tanhf(PV(193 + lane));
            float beta_w = softplusf(PV(257));
            float er1 = sigmf(PV(258 + lane)), er2 = sigmf(PV(322 + lane));
            float ad1 = tanhf(PV(386 + lane)), ad2 = tanhf(PV(450 + lane));
#undef PV
            float M1[4], M2[4];
#pragma unroll
            for (int s = 0; s < 4; ++s) {
                M1[s] = sM[row * 512 + s * 128 + lane];
                M2[s] = sM[row * 512 + s * 128 + 64 + lane];
            }
            float nkr = sqrtf(wred64(kr1 * kr1 + kr2 * kr2)) + 1e-8f;
            float nkw = sqrtf(wred64(kw1 * kw1 + kw2 * kw2)) + 1e-8f;
            float Kr[4], Kw[4];
#pragma unroll
            for (int s = 0; s < 4; ++s) {
                float nM = sqrtf(wred64(M1[s] * M1[s] + M2[s] * M2[s])) + 1e-8f;
                float dr = wred64(kr1 * M1[s] + kr2 * M2[s]);
                float dw = wred64(kw1 * M1[s] + kw2 * M2[s]);
                Kr[s] = dr / (nkr * nM);
                Kw[s] = dw / (nkw * nM);
            }
            float wr_[4], ww_[4];
            {
                float mx = fmaxf(fmaxf(beta_r * Kr[0], beta_r * Kr[1]),
                                 fmaxf(beta_r * Kr[2], beta_r * Kr[3]));
                float sum = 0.f;
#pragma unroll
                for (int s = 0; s < 4; ++s) { wr_[s] = expf(beta_r * Kr[s] - mx); sum += wr_[s]; }
                float inv = 1.f / sum;
#pragma unroll
                for (int s = 0; s < 4; ++s) wr_[s] *= inv;
            }
            {
                float mx = fmaxf(fmaxf(beta_w * Kw[0], beta_w * Kw[1]),
                                 fmaxf(beta_w * Kw[2], beta_w * Kw[3]));
                float sum = 0.f;
#pragma unroll
                for (int s = 0; s < 4; ++s) { ww_[s] = expf(beta_w * Kw[s] - mx); sum += ww_[s]; }
                float inv = 1.f / sum;
#pragma unroll
                for (int s = 0; s < 4; ++s) ww_[s] *= inv;
            }
            float rn1 = 0.f, rn2 = 0.f;
#pragma unroll
            for (int s = 0; s < 4; ++s) { rn1 += wr_[s] * M1[s]; rn2 += wr_[s] * M2[s]; }
            float mt = sMask[row * TT + t];
            bool vld = mt > 0.f;
            if (vld) {
#pragma unroll
                for (int s = 0; s < 4; ++s) {
                    sM[row * 512 + s * 128 + lane]      = M1[s] * (1.f - ww_[s] * er1) + ww_[s] * ad1;
                    sM[row * 512 + s * 128 + 64 + lane] = M2[s] * (1.f - ww_[s] * er2) + ww_[s] * ad2;
                }
                act16[row * 200 + lane]      = (_Float16)rn1;   // committed read
                act16[row * 200 + 64 + lane] = (_Float16)rn2;
            }
            if (t == ts) {
                // out = [h_new, read_new] @ Wo^T + bo  (unmasked values)
                float* stash = &sGI2[(t & 1) * 1536 + row * 192];
                stash[lane] = rn1; stash[64 + lane] = rn2;
                __asm__ volatile("s_waitcnt lgkmcnt(0)" ::: "memory");
                float acc = bo[lane];
                const float* wo = Wo + lane * GG;
                for (int k = 0; k < 64; ++k)  acc += sHnF[row * 64 + k] * wo[k];
                for (int k = 0; k < 128; ++k) acc += stash[k] * wo[64 + k];
                if (!vld) acc = 0.f;
                last_out[(size_t)(b0 + row) * 64 + lane] = acc;
            }
        }
        __syncthreads();                                   // B4
    }
}

// ---------------- K3: final MLP head --------------------------------------------
__global__ __launch_bounds__(128) void final_mlp(
    const int* __restrict__ item, const int* __restrict__ cate,
    const float* __restrict__ emb,
    const float* __restrict__ hist_sum, const float* __restrict__ last_out,
    const float* __restrict__ fc1w, const float* __restrict__ fc1b,
    const float* __restrict__ pa1,
    const float* __restrict__ fc2w, const float* __restrict__ fc2b,
    const float* __restrict__ pa2,
    const float* __restrict__ fc3w, const float* __restrict__ fc3b,
    float* __restrict__ out)
{
    __shared__ float sX[320], sH1[200], sH2[80];
    int b = blockIdx.x, tid = threadIdx.x;
    int it = item[b], ct = cate[b];
    for (int i = tid; i < 320; i += 128) {
        float val;
        if (i < 64)       val = emb[(size_t)it * 64 + i];
        else if (i < 128) val = emb[(size_t)ct * 64 + (i - 64)];
        else if (i < 256) val = hist_sum[(size_t)b * 128 + (i - 128)];
        else              val = last_out[(size_t)b * 64 + (i - 256)];
        sX[i] = val;
    }
    __syncthreads();
    float a1 = pa1[0];
    for (int o = tid; o < 200; o += 128) {
        const float4* w = (const float4*)(fc1w + o * 320);
        float acc = fc1b[o];
#pragma unroll
        for (int q = 0; q < 80; ++q) acc += dot4(w[q], *(const float4*)&sX[q * 4]);
        sH1[o] = acc > 0.f ? acc : a1 * acc;
    }
    __syncthreads();
    float a2 = pa2[0];
    for (int o = tid; o < 80; o += 128) {
        const float4* w = (const float4*)(fc2w + o * 200);
        float acc = fc2b[o];
#pragma unroll
        for (int q = 0; q < 50; ++q) acc += dot4(w[q], *(const float4*)&sH1[q * 4]);
        sH2[o] = acc > 0.f ? acc : a2 * acc;
    }
    __syncthreads();
    if (tid < 2) {
        const float4* w = (const float4*)(fc3w + tid * 80);
        float acc = fc3b[tid];
#pragma unroll
        for (int q = 0; q < 20; ++q) acc += dot4(w[q], *(const float4*)&sH2[q * 4]);
        out[b * 2 + tid] = acc;
    }
}

extern "C" void kernel_launch(void* const* d_in, const int* in_sizes, int n_in,
                              void* d_out, int out_size, void* d_ws, size_t ws_size,
                              hipStream_t stream) {
    (void)in_sizes; (void)n_in; (void)out_size; (void)ws_size;
    const int*   item      = (const int*)d_in[0];
    const int*   cate      = (const int*)d_in[1];
    const int*   hist_item = (const int*)d_in[2];
    const int*   hist_cate = (const int*)d_in[3];
    const float* mask = (const float*)d_in[4];
    const float* emb  = (const float*)d_in[5];
    const float* Wih  = (const float*)d_in[6];
    const float* Whh  = (const float*)d_in[7];
    const float* bih  = (const float*)d_in[8];
    const float* bhh  = (const float*)d_in[9];
    const float* Wp   = (const float*)d_in[10];
    const float* bp   = (const float*)d_in[11];
    const float* Wo   = (const float*)d_in[12];
    const float* bo   = (const float*)d_in[13];
    const float* M0   = (const float*)d_in[14];
    const float* fc1w = (const float*)d_in[15];
    const float* fc1b = (const float*)d_in[16];
    const float* pa1  = (const float*)d_in[17];
    const float* fc2w = (const float*)d_in[18];
    const float* fc2b = (const float*)d_in[19];
    const float* pa2  = (const float*)d_in[20];
    const float* fc3w = (const float*)d_in[21];
    const float* fc3b = (const float*)d_in[22];

    float* GIi = (float*)d_ws;                                   // V*192 f32
    float* GIc = GIi + (size_t)VV * GG;                          // V*192 f32
    float* hist_sum = GIc + (size_t)VV * GG;                     // B*128 f32
    float* last_out = hist_sum + (size_t)BB * 128;               // B*64 f32
    int* seqlen = (int*)(last_out + (size_t)BB * 64);            // B int

    build_tables<<<(VV + 63) / 64, 192, 0, stream>>>(emb, Wih, bih, GIi, GIc);
    hist_stats<<<BB, 128, 0, stream>>>(hist_item, hist_cate, mask, emb, hist_sum, seqlen);
    mimn_rnn<<<BB / RPB, 768, 0, stream>>>(hist_item, hist_cate, mask, Wih, Whh, bhh,
                                           Wp, bp, Wo, bo, M0, GIi, GIc, seqlen, last_out);
    final_mlp<<<BB, 128, 0, stream>>>(item, cate, emb, hist_sum, last_out,
                                      fc1w, fc1b, pa1, fc2w, fc2b, pa2, fc3w, fc3b,
                                      (float*)d_out);
}